// Round 13
// baseline (189.548 us; speedup 1.0000x reference)
//
#include <hip/hip_runtime.h>

#define EPS 1e-5f
#define B 16
#define CH 22
#define T_IN 1001
#define F 36
#define RF 65
#define T1 937            // T_IN - RF + 1
#define FC 792            // F*CH
#define KW 99             // sconv per-wave K slice (FC/8)
#define UN 885            // valid u range for Q/E
#define PSPAN 304         // qconv staged span per f row
#define KS 15
#define GN 295
#define WN 129
#define M43 43
#define BF 576            // B*F
#define FLAT 1548         // F*43

// workspace float offsets
#define H2_OFF  0                 // 576*937       =   539,712
#define EP_OFF  539712            // + 8*576*885   = 4,078,080
#define WTT_OFF 4617792           // + 36*65       =     2,340
#define WST_OFF 4620132           // + 792*36      =    28,512
#define WCT_OFF 4648644           // + 36*15*36    =    19,440
#define BN_OFF  4668084           // + 6*36        =       216
#define H1_OFF  4668352           // h1 fp32 (slabbed if tight)

__device__ __forceinline__ float elu_f(float v) {
    return v > 0.f ? v : (__expf(v) - 1.f);
}

// ---- prep: transpose weights + bn scale/offset + init out with bias --------
__global__ __launch_bounds__(256) void k_prep(
    const float* __restrict__ w_t, const float* __restrict__ w_s,
    const float* __restrict__ w_c,
    const float* __restrict__ b_t, const float* __restrict__ g_t,
    const float* __restrict__ be_t,const float* __restrict__ m_t,
    const float* __restrict__ v_t,
    const float* __restrict__ b_s, const float* __restrict__ g_s,
    const float* __restrict__ be_s,const float* __restrict__ m_s,
    const float* __restrict__ v_s,
    const float* __restrict__ b_c, const float* __restrict__ g_c,
    const float* __restrict__ be_c,const float* __restrict__ m_c,
    const float* __restrict__ v_c, const float* __restrict__ b_fc,
    float* __restrict__ wtT, float* __restrict__ wsT,
    float* __restrict__ wcT, float* __restrict__ bnz,
    float* __restrict__ out)
{
    int i = blockIdx.x * 256 + threadIdx.x;
    if (i < F * RF)     { int k = i / F,  fi = i % F; wtT[i] = w_t[fi * RF + k]; }
    if (i < FC * F)     { int fc = i / F, fo = i % F; wsT[i] = w_s[fo * FC + fc]; }
    if (i < F * KS * F) { int fk = i / F, fo = i % F; int f = fk / KS, k = fk % KS;
                          wcT[i] = w_c[(fo * F + f) * KS + k]; }
    if (i < F) {
        float s1 = g_t[i] * rsqrtf(v_t[i] + EPS);
        bnz[i]          = s1;
        bnz[F + i]      = (b_t[i] - m_t[i]) * s1 + be_t[i];
        float s2 = g_s[i] * rsqrtf(v_s[i] + EPS);
        bnz[2 * F + i]  = s2;
        bnz[3 * F + i]  = (b_s[i] - m_s[i]) * s2 + be_s[i];
        float s3 = g_c[i] * rsqrtf(v_c[i] + EPS);
        bnz[4 * F + i]  = s3;
        bnz[5 * F + i]  = (b_c[i] - m_c[i]) * s3 + be_c[i];
    }
    if (i < B * 4) out[i] = b_fc[i & 3];
}

// ---- K1a: temporal conv + bn + elu -> h1 (fp32), in-block k-split x2 -------
// grid (ceil(TSeff/256), CH, B); 512 thr = 8 waves = 4 t-subchunks x 2 k-halves
__global__ __launch_bounds__(512) void k_tconv(
    const float* __restrict__ x, const float* __restrict__ wtT,
    const float* __restrict__ bnz, float* __restrict__ h1,
    int t_base, int TS, int TSeff)
{
    __shared__ float Ls[4 * F * 64];   // 36.9 KB
    const int tid = threadIdx.x;
    const int lane = tid & 63;
    const int w = __builtin_amdgcn_readfirstlane(tid >> 6);   // 0..7
    const int tsub = w & 3, khalf = w >> 2;
    const int b = blockIdx.z, ch = blockIdx.y;
    const int tl0 = blockIdx.x * 256 + tsub * 64;
    int t = t_base + tl0 + lane;
    int tc = t < (T1 - 1) ? t : (T1 - 1);
    const float* xp = x + (b * CH + ch) * T_IN + tc;
    const int k0 = khalf * 32;

    float acc[F];
    #pragma unroll
    for (int j = 0; j < F; ++j) acc[j] = 0.f;

    // 8 float4 loads cover 32 k-steps (dwordx4 is dword-aligned-safe on CDNA)
    #pragma unroll 4
    for (int kk = 0; kk < 8; ++kk) {
        float4 xv4 = *(const float4*)(xp + k0 + 4 * kk);
        const float* wr0 = wtT + (k0 + 4 * kk + 0) * F;
        const float* wr1 = wtT + (k0 + 4 * kk + 1) * F;
        const float* wr2 = wtT + (k0 + 4 * kk + 2) * F;
        const float* wr3 = wtT + (k0 + 4 * kk + 3) * F;
        #pragma unroll
        for (int j = 0; j < F; ++j) {
            acc[j] += xv4.x * wr0[j];
            acc[j] += xv4.y * wr1[j];
            acc[j] += xv4.z * wr2[j];
            acc[j] += xv4.w * wr3[j];
        }
    }
    if (khalf == 1) {   // tail k = 64
        float xv = xp[64];
        const float* wr = wtT + 64 * F;
        #pragma unroll
        for (int j = 0; j < F; ++j) acc[j] += xv * wr[j];
    }

    float* row = &Ls[(size_t)tsub * (F * 64)];
    if (khalf == 0) {
        #pragma unroll
        for (int j = 0; j < F; ++j) row[j * 64 + lane] = acc[j];
    }
    __syncthreads();
    if (khalf == 1) {
        #pragma unroll
        for (int j = 0; j < F; ++j) row[j * 64 + lane] += acc[j];
    }
    __syncthreads();

    // epilogue: 4*36*64 = 9216 outputs / 512 thr = 18 each
    for (int i = tid; i < 4 * F * 64; i += 512) {
        int l2 = i & 63;
        int fo = (i >> 6) % F;
        int ts2 = i / (F * 64);
        int tloc = blockIdx.x * 256 + ts2 * 64 + l2;
        int tg = t_base + tloc;
        if (tloc < TSeff && tg < T1) {
            float s1 = bnz[fo], o1 = bnz[F + fo];
            h1[((size_t)(b * F + fo) * CH + ch) * TS + tloc] =
                elu_f(Ls[i] * s1 + o1);
        }
    }
}

// ---- K1b: 1x1 spatial conv, in-block 8-way split-K + bn + elu -> h2 --------
// grid (ceil(TSeff/64), B); 512 thr = 8 waves = 8 K-slices of same 64 t;
// LDS reduce folded to 4 rows (waves 4-7 add into rows 0-3) -> 36.9 KB.
__global__ __launch_bounds__(512) void k_sconv(
    const float* __restrict__ h1, const float* __restrict__ wsT,
    const float* __restrict__ bnz, float* __restrict__ h2,
    int t_base, int TS, int TSeff)
{
    __shared__ float Ls[4 * F * 64];   // 36.9 KB
    const int tid = threadIdx.x;
    const int lane = tid & 63;
    const int w = __builtin_amdgcn_readfirstlane(tid >> 6);   // K-slice 0..7
    const int b = blockIdx.y;
    const int tl0 = blockIdx.x * 64;
    int tl = tl0 + lane;
    int tlc = tl < (TSeff - 1) ? tl : (TSeff - 1);

    const float* hq = h1 + ((size_t)b * FC + w * KW) * TS + tlc;
    const float* wb = wsT + (w * KW) * F;

    float acc[F];
    #pragma unroll
    for (int j = 0; j < F; ++j) acc[j] = 0.f;

    #pragma unroll 11
    for (int fc = 0; fc < KW; ++fc) {
        float hv = hq[(size_t)fc * TS];        // 256B coalesced, L2/L3
        const float* wr = wb + fc * F;         // wave-uniform -> wide s_load
        #pragma unroll
        for (int j = 0; j < F; ++j) acc[j] += hv * wr[j];
    }

    float* row = &Ls[(size_t)(w & 3) * (F * 64)];
    if (w < 4) {
        #pragma unroll
        for (int j = 0; j < F; ++j) row[j * 64 + lane] = acc[j];
    }
    __syncthreads();
    if (w >= 4) {
        #pragma unroll
        for (int j = 0; j < F; ++j) row[j * 64 + lane] += acc[j];
    }
    __syncthreads();

    for (int i = tid; i < F * 64; i += 512) {
        float s = Ls[i] + Ls[F * 64 + i] + Ls[2 * F * 64 + i] + Ls[3 * F * 64 + i];
        int fo = i >> 6;
        int tloc2 = tl0 + (i & 63);
        int tg = t_base + tloc2;
        if (tloc2 < TSeff) {
            float s2 = bnz[2 * F + fo], o2 = bnz[3 * F + fo];
            h2[(b * F + fo) * T1 + tg] = elu_f(s * s2 + o2);
        }
    }
}

// ---- K2: fused pool3 + dilated conv over h2 -> raw partials Ep -------------
// grid (4, 8, B); 4 waves = 4 u-subchunks; wave = 64 u x 36 fo
__global__ __launch_bounds__(256) void k_qconv(
    const float* __restrict__ h2, const float* __restrict__ wcT,
    float* __restrict__ Ep)
{
    __shared__ float Ps[5 * PSPAN];   // 6.1 KB
    const int tid = threadIdx.x;
    const int slice = blockIdx.y, b = blockIdx.z;
    const int u0 = blockIdx.x * 256;
    const int f_base = slice < 4 ? slice * 5 : 20 + (slice - 4) * 4;
    const int nf     = slice < 4 ? 5 : 4;

    for (int i = tid; i < nf * PSPAN; i += 256) {
        int fl = i / PSPAN, j = i % PSPAN;
        const float* hr = h2 + (size_t)(b * F + f_base + fl) * T1;
        int s = u0 + j;
        int s0 = s     < T1 - 1 ? s     : T1 - 1;
        int s1 = s + 1 < T1 - 1 ? s + 1 : T1 - 1;
        int s2 = s + 2 < T1 - 1 ? s + 2 : T1 - 1;
        Ps[i] = (hr[s0] + hr[s1] + hr[s2]) * (1.f / 3.f);
    }
    __syncthreads();

    const int lu = tid;                        // wave = 64 consecutive u

    float acc[F];
    #pragma unroll
    for (int j = 0; j < F; ++j) acc[j] = 0.f;

    for (int fl = 0; fl < nf; ++fl) {
        const int pb = fl * PSPAN + lu;
        #pragma unroll 5
        for (int k = 0; k < KS; ++k) {
            float pv = Ps[pb + 3 * k];
            const float* wr = wcT + ((f_base + fl) * KS + k) * F;  // uniform
            #pragma unroll
            for (int j = 0; j < F; ++j) acc[j] += pv * wr[j];
        }
    }

    int u_g = u0 + lu;
    if (u_g < UN) {
        #pragma unroll
        for (int j = 0; j < F; ++j)
            Ep[(((size_t)slice * B + b) * F + j) * UN + u_g] = acc[j];
    }
}

// ---- K3: combine Ep + bn_c + elu, window sums, fused FC -> atomicAdd out ---
__global__ __launch_bounds__(256) void k_wins(
    const float* __restrict__ Ep, const float* __restrict__ bnz,
    const float* __restrict__ w_fc, float* __restrict__ out)
{
    __shared__ float Es[UN];
    __shared__ float G[GN];
    __shared__ float Ws[WN];
    __shared__ float Sm[M43];
    const int tid = threadIdx.x;
    const int bf = blockIdx.x;
    const int b = bf / F, f = bf % F;
    const float sc = bnz[4 * F + f];
    const float oc = bnz[5 * F + f];
    for (int i = tid; i < UN; i += 256) {
        float s = 0.f;
        #pragma unroll
        for (int sl = 0; sl < 8; ++sl)
            s += Ep[((size_t)sl * BF + bf) * UN + i];
        Es[i] = elu_f(s * sc + oc);
    }
    __syncthreads();
    for (int q = tid; q < GN; q += 256)
        G[q] = Es[3 * q] + Es[3 * q + 1] + Es[3 * q + 2];
    __syncthreads();
    if (tid < WN) {
        float a = 0.f;
        for (int q = tid; q < tid + 167; ++q) a += G[q];
        Ws[tid] = a;
    }
    __syncthreads();
    if (tid < M43)
        Sm[tid] = (Ws[3 * tid] + Ws[3 * tid + 1] + Ws[3 * tid + 2]) * (1.f / 3.f);
    __syncthreads();
    if (tid < 4) {
        const float* wr = w_fc + tid * FLAT + f * M43;
        float a = 0.f;
        #pragma unroll 43
        for (int m = 0; m < M43; ++m) a += Sm[m] * wr[m];
        atomicAdd(&out[b * 4 + tid], a * (1.f / 501.f));
    }
}

extern "C" void kernel_launch(void* const* d_in, const int* in_sizes, int n_in,
                              void* d_out, int out_size, void* d_ws, size_t ws_size,
                              hipStream_t stream) {
    const float* x    = (const float*)d_in[0];
    const float* w_t  = (const float*)d_in[1];
    const float* b_t  = (const float*)d_in[2];
    const float* g_t  = (const float*)d_in[3];
    const float* be_t = (const float*)d_in[4];
    const float* m_t  = (const float*)d_in[5];
    const float* v_t  = (const float*)d_in[6];
    const float* w_s  = (const float*)d_in[7];
    const float* b_s  = (const float*)d_in[8];
    const float* g_s  = (const float*)d_in[9];
    const float* be_s = (const float*)d_in[10];
    const float* m_s  = (const float*)d_in[11];
    const float* v_s  = (const float*)d_in[12];
    const float* w_c  = (const float*)d_in[13];
    const float* b_c  = (const float*)d_in[14];
    const float* g_c  = (const float*)d_in[15];
    const float* be_c = (const float*)d_in[16];
    const float* m_c  = (const float*)d_in[17];
    const float* v_c  = (const float*)d_in[18];
    const float* w_fc = (const float*)d_in[19];
    const float* b_fc = (const float*)d_in[20];

    float* ws  = (float*)d_ws;
    float* h2  = ws + H2_OFF;
    float* Ep  = ws + EP_OFF;
    float* wtT = ws + WTT_OFF;
    float* wsT = ws + WST_OFF;
    float* wcT = ws + WCT_OFF;
    float* bnz = ws + BN_OFF;
    float* h1  = ws + H1_OFF;
    float* out = (float*)d_out;

    // slab the t-dimension so h1 fits whatever scratch we actually have
    long long availF = (long long)(ws_size / 4) - (long long)H1_OFF;
    long long tsl = availF / (B * FC);
    int TS;
    if (tsl >= T1) TS = T1;
    else { TS = (int)(tsl & ~63LL); if (TS < 64) TS = 64; }
    int nslab = (T1 + TS - 1) / TS;

    k_prep<<<dim3(112), 256, 0, stream>>>(
        w_t, w_s, w_c, b_t, g_t, be_t, m_t, v_t,
        b_s, g_s, be_s, m_s, v_s, b_c, g_c, be_c, m_c, v_c, b_fc,
        wtT, wsT, wcT, bnz, out);

    for (int sl = 0; sl < nslab; ++sl) {
        int t_base = sl * TS;
        int TSeff = T1 - t_base; if (TSeff > TS) TSeff = TS;
        k_tconv<<<dim3((TSeff + 255) / 256, CH, B), 512, 0, stream>>>(
            x, wtT, bnz, h1, t_base, TS, TSeff);
        k_sconv<<<dim3((TSeff + 63) / 64, B), 512, 0, stream>>>(
            h1, wsT, bnz, h2, t_base, TS, TSeff);
    }

    k_qconv<<<dim3(4, 8, B), 256, 0, stream>>>(h2, wcT, Ep);
    k_wins<<<dim3(BF), 256, 0, stream>>>(Ep, bnz, w_fc, out);
}

// Round 14
// 178.722 us; speedup vs baseline: 1.0606x; 1.0606x over previous
//
#include <hip/hip_runtime.h>

#define EPS 1e-5f
#define B 16
#define CH 22
#define T_IN 1001
#define F 36
#define RF 65
#define T1 937            // T_IN - RF + 1
#define FC 792            // F*CH
#define KW 99             // sconv per-wave K slice (FC/8)
#define FH 18             // sconv per-block fo half
#define UN 885            // valid u range for Q/E
#define PSPAN 304         // qconv staged span per f row
#define KS 15
#define GN 295
#define WN 129
#define M43 43
#define BF 576            // B*F
#define FLAT 1548         // F*43

// workspace float offsets
#define H2_OFF  0                 // 576*937       =   539,712
#define EP_OFF  539712            // + 8*576*885   = 4,078,080
#define WTT_OFF 4617792           // + 36*65       =     2,340
#define WST_OFF 4620132           // + 792*36      =    28,512
#define WCT_OFF 4648644           // + 36*15*36    =    19,440
#define BN_OFF  4668084           // + 6*36        =       216
#define H1_OFF  4668352           // h1 fp32 (slabbed if tight)

__device__ __forceinline__ float elu_f(float v) {
    return v > 0.f ? v : (__expf(v) - 1.f);
}

// ---- prep: transpose weights + bn scale/offset + init out with bias --------
__global__ __launch_bounds__(256) void k_prep(
    const float* __restrict__ w_t, const float* __restrict__ w_s,
    const float* __restrict__ w_c,
    const float* __restrict__ b_t, const float* __restrict__ g_t,
    const float* __restrict__ be_t,const float* __restrict__ m_t,
    const float* __restrict__ v_t,
    const float* __restrict__ b_s, const float* __restrict__ g_s,
    const float* __restrict__ be_s,const float* __restrict__ m_s,
    const float* __restrict__ v_s,
    const float* __restrict__ b_c, const float* __restrict__ g_c,
    const float* __restrict__ be_c,const float* __restrict__ m_c,
    const float* __restrict__ v_c, const float* __restrict__ b_fc,
    float* __restrict__ wtT, float* __restrict__ wsT,
    float* __restrict__ wcT, float* __restrict__ bnz,
    float* __restrict__ out)
{
    int i = blockIdx.x * 256 + threadIdx.x;
    if (i < F * RF)     { int k = i / F,  fi = i % F; wtT[i] = w_t[fi * RF + k]; }
    if (i < FC * F)     { int fc = i / F, fo = i % F; wsT[i] = w_s[fo * FC + fc]; }
    if (i < F * KS * F) { int fk = i / F, fo = i % F; int f = fk / KS, k = fk % KS;
                          wcT[i] = w_c[(fo * F + f) * KS + k]; }
    if (i < F) {
        float s1 = g_t[i] * rsqrtf(v_t[i] + EPS);
        bnz[i]          = s1;
        bnz[F + i]      = (b_t[i] - m_t[i]) * s1 + be_t[i];
        float s2 = g_s[i] * rsqrtf(v_s[i] + EPS);
        bnz[2 * F + i]  = s2;
        bnz[3 * F + i]  = (b_s[i] - m_s[i]) * s2 + be_s[i];
        float s3 = g_c[i] * rsqrtf(v_c[i] + EPS);
        bnz[4 * F + i]  = s3;
        bnz[5 * F + i]  = (b_c[i] - m_c[i]) * s3 + be_c[i];
    }
    if (i < B * 4) out[i] = b_fc[i & 3];
}

// ---- K1a: temporal conv + bn + elu -> h1 (fp32) ----------------------------
// grid (ceil(TSeff/256), CH, B); 4 waves; wave = 64 consecutive t x 36 fi.
__global__ __launch_bounds__(256) void k_tconv(
    const float* __restrict__ x, const float* __restrict__ wtT,
    const float* __restrict__ bnz, float* __restrict__ h1,
    int t_base, int TS, int TSeff)
{
    const int tloc = blockIdx.x * 256 + threadIdx.x;
    const int b = blockIdx.z, ch = blockIdx.y;
    int t = t_base + tloc;
    int tc = t < (T1 - 1) ? t : (T1 - 1);
    const float* xp = x + (b * CH + ch) * T_IN + tc;

    float acc[F];
    #pragma unroll
    for (int j = 0; j < F; ++j) acc[j] = 0.f;

    // 16 float4 loads cover k = 0..63 (dwordx4 is dword-aligned-safe on CDNA)
    #pragma unroll 4
    for (int kk = 0; kk < 16; ++kk) {
        float4 xv4 = *(const float4*)(xp + 4 * kk);
        const float* wr0 = wtT + (4 * kk + 0) * F;
        const float* wr1 = wtT + (4 * kk + 1) * F;
        const float* wr2 = wtT + (4 * kk + 2) * F;
        const float* wr3 = wtT + (4 * kk + 3) * F;
        #pragma unroll
        for (int j = 0; j < F; ++j) {
            acc[j] += xv4.x * wr0[j];
            acc[j] += xv4.y * wr1[j];
            acc[j] += xv4.z * wr2[j];
            acc[j] += xv4.w * wr3[j];
        }
    }
    {   // tail k = 64
        float xv = xp[64];
        const float* wr = wtT + 64 * F;
        #pragma unroll
        for (int j = 0; j < F; ++j) acc[j] += xv * wr[j];
    }

    if (t < T1 && tloc < TSeff) {
        #pragma unroll
        for (int j = 0; j < F; ++j) {
            float s1 = bnz[j], o1 = bnz[F + j];
            h1[((size_t)(b * F + j) * CH + ch) * TS + tloc] =
                elu_f(acc[j] * s1 + o1);
        }
    }
}

// ---- K1b: 1x1 spatial conv, 8-way in-block split-K x 2-way fo-split --------
// grid (ceil(TSeff/64), 2, B); 512 thr = 8 waves = 8 K-slices of same 64 t;
// block computes 18 of the 36 fo (blockIdx.y) -> 2x waves vs R10, LDS 36.9 KB
__global__ __launch_bounds__(512) void k_sconv(
    const float* __restrict__ h1, const float* __restrict__ wsT,
    const float* __restrict__ bnz, float* __restrict__ h2,
    int t_base, int TS, int TSeff)
{
    __shared__ float Ls[8 * FH * 64];   // 36.9 KB
    const int tid = threadIdx.x;
    const int lane = tid & 63;
    const int w = __builtin_amdgcn_readfirstlane(tid >> 6);   // K-slice 0..7
    const int fo0 = blockIdx.y * FH;
    const int b = blockIdx.z;
    const int tl0 = blockIdx.x * 64;
    int tl = tl0 + lane;
    int tlc = tl < (TSeff - 1) ? tl : (TSeff - 1);

    const float* hq = h1 + ((size_t)b * FC + w * KW) * TS + tlc;
    const float* wb = wsT + (w * KW) * F + fo0;

    float acc[FH];
    #pragma unroll
    for (int j = 0; j < FH; ++j) acc[j] = 0.f;

    #pragma unroll 11
    for (int fc = 0; fc < KW; ++fc) {
        float hv = hq[(size_t)fc * TS];        // 256B coalesced, L2/L3
        const float* wr = wb + fc * F;         // wave-uniform 18 consecutive
        #pragma unroll
        for (int j = 0; j < FH; ++j) acc[j] += hv * wr[j];
    }

    #pragma unroll
    for (int j = 0; j < FH; ++j) Ls[(w * FH + j) * 64 + lane] = acc[j];
    __syncthreads();

    for (int i = tid; i < FH * 64; i += 512) {
        float s = 0.f;
        #pragma unroll
        for (int wq = 0; wq < 8; ++wq) s += Ls[wq * (FH * 64) + i];
        int fo = fo0 + (i >> 6);
        int tloc2 = tl0 + (i & 63);
        int tg = t_base + tloc2;
        if (tloc2 < TSeff) {
            float s2 = bnz[2 * F + fo], o2 = bnz[3 * F + fo];
            h2[(b * F + fo) * T1 + tg] = elu_f(s * s2 + o2);
        }
    }
}

// ---- K2: fused pool3 + dilated conv over h2 -> raw partials Ep -------------
// grid (4, 8, B); 4 waves = 4 u-subchunks; wave = 64 u x 36 fo
__global__ __launch_bounds__(256) void k_qconv(
    const float* __restrict__ h2, const float* __restrict__ wcT,
    float* __restrict__ Ep)
{
    __shared__ float Ps[5 * PSPAN];   // 6.1 KB
    const int tid = threadIdx.x;
    const int slice = blockIdx.y, b = blockIdx.z;
    const int u0 = blockIdx.x * 256;
    const int f_base = slice < 4 ? slice * 5 : 20 + (slice - 4) * 4;
    const int nf     = slice < 4 ? 5 : 4;

    for (int i = tid; i < nf * PSPAN; i += 256) {
        int fl = i / PSPAN, j = i % PSPAN;
        const float* hr = h2 + (size_t)(b * F + f_base + fl) * T1;
        int s = u0 + j;
        int s0 = s     < T1 - 1 ? s     : T1 - 1;
        int s1 = s + 1 < T1 - 1 ? s + 1 : T1 - 1;
        int s2 = s + 2 < T1 - 1 ? s + 2 : T1 - 1;
        Ps[i] = (hr[s0] + hr[s1] + hr[s2]) * (1.f / 3.f);
    }
    __syncthreads();

    const int lu = tid;                        // wave = 64 consecutive u

    float acc[F];
    #pragma unroll
    for (int j = 0; j < F; ++j) acc[j] = 0.f;

    for (int fl = 0; fl < nf; ++fl) {
        const int pb = fl * PSPAN + lu;
        #pragma unroll 5
        for (int k = 0; k < KS; ++k) {
            float pv = Ps[pb + 3 * k];
            const float* wr = wcT + ((f_base + fl) * KS + k) * F;  // uniform
            #pragma unroll
            for (int j = 0; j < F; ++j) acc[j] += pv * wr[j];
        }
    }

    int u_g = u0 + lu;
    if (u_g < UN) {
        #pragma unroll
        for (int j = 0; j < F; ++j)
            Ep[(((size_t)slice * B + b) * F + j) * UN + u_g] = acc[j];
    }
}

// ---- K3: combine Ep + bn_c + elu, window sums, fused FC -> atomicAdd out ---
__global__ __launch_bounds__(256) void k_wins(
    const float* __restrict__ Ep, const float* __restrict__ bnz,
    const float* __restrict__ w_fc, float* __restrict__ out)
{
    __shared__ float Es[UN];
    __shared__ float G[GN];
    __shared__ float Ws[WN];
    __shared__ float Sm[M43];
    const int tid = threadIdx.x;
    const int bf = blockIdx.x;
    const int b = bf / F, f = bf % F;
    const float sc = bnz[4 * F + f];
    const float oc = bnz[5 * F + f];
    for (int i = tid; i < UN; i += 256) {
        float s = 0.f;
        #pragma unroll
        for (int sl = 0; sl < 8; ++sl)
            s += Ep[((size_t)sl * BF + bf) * UN + i];
        Es[i] = elu_f(s * sc + oc);
    }
    __syncthreads();
    for (int q = tid; q < GN; q += 256)
        G[q] = Es[3 * q] + Es[3 * q + 1] + Es[3 * q + 2];
    __syncthreads();
    if (tid < WN) {
        float a = 0.f;
        for (int q = tid; q < tid + 167; ++q) a += G[q];
        Ws[tid] = a;
    }
    __syncthreads();
    if (tid < M43)
        Sm[tid] = (Ws[3 * tid] + Ws[3 * tid + 1] + Ws[3 * tid + 2]) * (1.f / 3.f);
    __syncthreads();
    if (tid < 4) {
        const float* wr = w_fc + tid * FLAT + f * M43;
        float a = 0.f;
        #pragma unroll 43
        for (int m = 0; m < M43; ++m) a += Sm[m] * wr[m];
        atomicAdd(&out[b * 4 + tid], a * (1.f / 501.f));
    }
}

extern "C" void kernel_launch(void* const* d_in, const int* in_sizes, int n_in,
                              void* d_out, int out_size, void* d_ws, size_t ws_size,
                              hipStream_t stream) {
    const float* x    = (const float*)d_in[0];
    const float* w_t  = (const float*)d_in[1];
    const float* b_t  = (const float*)d_in[2];
    const float* g_t  = (const float*)d_in[3];
    const float* be_t = (const float*)d_in[4];
    const float* m_t  = (const float*)d_in[5];
    const float* v_t  = (const float*)d_in[6];
    const float* w_s  = (const float*)d_in[7];
    const float* b_s  = (const float*)d_in[8];
    const float* g_s  = (const float*)d_in[9];
    const float* be_s = (const float*)d_in[10];
    const float* m_s  = (const float*)d_in[11];
    const float* v_s  = (const float*)d_in[12];
    const float* w_c  = (const float*)d_in[13];
    const float* b_c  = (const float*)d_in[14];
    const float* g_c  = (const float*)d_in[15];
    const float* be_c = (const float*)d_in[16];
    const float* m_c  = (const float*)d_in[17];
    const float* v_c  = (const float*)d_in[18];
    const float* w_fc = (const float*)d_in[19];
    const float* b_fc = (const float*)d_in[20];

    float* ws  = (float*)d_ws;
    float* h2  = ws + H2_OFF;
    float* Ep  = ws + EP_OFF;
    float* wtT = ws + WTT_OFF;
    float* wsT = ws + WST_OFF;
    float* wcT = ws + WCT_OFF;
    float* bnz = ws + BN_OFF;
    float* h1  = ws + H1_OFF;
    float* out = (float*)d_out;

    // slab the t-dimension so h1 fits whatever scratch we actually have
    long long availF = (long long)(ws_size / 4) - (long long)H1_OFF;
    long long tsl = availF / (B * FC);
    int TS;
    if (tsl >= T1) TS = T1;
    else { TS = (int)(tsl & ~63LL); if (TS < 64) TS = 64; }
    int nslab = (T1 + TS - 1) / TS;

    k_prep<<<dim3(112), 256, 0, stream>>>(
        w_t, w_s, w_c, b_t, g_t, be_t, m_t, v_t,
        b_s, g_s, be_s, m_s, v_s, b_c, g_c, be_c, m_c, v_c, b_fc,
        wtT, wsT, wcT, bnz, out);

    for (int sl = 0; sl < nslab; ++sl) {
        int t_base = sl * TS;
        int TSeff = T1 - t_base; if (TSeff > TS) TSeff = TS;
        k_tconv<<<dim3((TSeff + 255) / 256, CH, B), 256, 0, stream>>>(
            x, wtT, bnz, h1, t_base, TS, TSeff);
        k_sconv<<<dim3((TSeff + 63) / 64, 2, B), 512, 0, stream>>>(
            h1, wsT, bnz, h2, t_base, TS, TSeff);
    }

    k_qconv<<<dim3(4, 8, B), 256, 0, stream>>>(h2, wcT, Ep);
    k_wins<<<dim3(BF), 256, 0, stream>>>(Ep, bnz, w_fc, out);
}